// Round 8
// baseline (194.648 us; speedup 1.0000x reference)
//
#include <hip/hip_runtime.h>

// Problem constants (from reference setup_inputs)
#define BB   8
#define PP   16384
#define KK   16384
#define NN   16
#define CIN  64
#define REL  3
#define CC   67
#define OUTC 64
#define PITCH_US 104       // ushorts per staged row: 96 data + 8 pad = 208 B

// History: r5 76us; r7 61us; r9 56us; r10 45us (bf16 image; -2x bytes ->
// 1.24x); r11/r12 64us (VGPR spill; launch_bounds CUDA min-BLOCKS
// semantics); r13 2x TLP: NULL; r14 dummy-CL: NULL; r15 -2x CLs: NULL;
// r16 +8x segments/instr: 1.5x WORSE (and SQ_LDS_BANK_CONFLICT invariant
// 491520 => conflicts are phase2/W-init, benign); r17 -2x instructions:
// NULL. 42-45us across ALL of it (~108k cyc). No static count explains
// 108k cyc -> latency exposure + hidden serialization, location unknown.
//
// Round 18: MEASUREMENT ROUND (pre-committed after r16; skipped once).
// Split the kernel into its halves as separate dispatches; rocprof gives
// per-dispatch dur_us:
//   probe_gather_kernel  = metadata + bpermute + gathers + unpack only
//   probe_nogather_kernel= everything EXCEPT gathers (synthetic gv)
//   graphconv_kernel     = real r13 body, runs LAST, overwrites out fully
// Readout (pre-committed):
//   H1 cap-on-outstanding: gather~35-45, nogather<=15 -> attack footprint
//   H2 interference:       both <=20 -> split into two kernels via ws
//   H3 per-wave chains:    both ~30-40 -> ILP restructure
// Harness dur_us regresses this round by design (~200+); real kernel's
// own dispatch should still read ~44us in the counter table.

typedef short s16x8 __attribute__((ext_vector_type(8)));   // 8 bf16 = 4 VGPRs
typedef float f32x4 __attribute__((ext_vector_type(4)));   // MFMA accum
typedef unsigned int u32x2 __attribute__((ext_vector_type(2)));

static __device__ __forceinline__ unsigned short bf16_rne(float f) {
    unsigned int u = __float_as_uint(f);
    u += 0x7FFF + ((u >> 16) & 1);          // round-to-nearest-even
    return (unsigned short)(u >> 16);
}

template <int PAT>
static __device__ __forceinline__ float swz_add(float v) {
    return v + __int_as_float(
        __builtin_amdgcn_ds_swizzle(__float_as_int(v), PAT));
}

// ---- pre-pass: feats fp32 -> bf16 (RNE) into workspace ----
__global__ __launch_bounds__(256) void feats_to_bf16_kernel(
    const float* __restrict__ f, unsigned short* __restrict__ o)
{
    const int i = blockIdx.x * 256 + threadIdx.x;   // one float4 per thread
    const float4 v = ((const float4*)f)[i];         // 16B coalesced read
    ushort4 r;
    r.x = bf16_rne(v.x); r.y = bf16_rne(v.y);
    r.z = bf16_rne(v.z); r.w = bf16_rne(v.w);
    ((ushort4*)o)[i] = r;                           // 8B coalesced write
}

// ==================== PROBE A: gather machinery only ====================
__global__ __launch_bounds__(512, 4)
void probe_gather_kernel(
    const unsigned short* __restrict__ fbf16,
    const int*   __restrict__ n_idxs,
    const float* __restrict__ neighbor_rel,
    const int*   __restrict__ neighbor_valid,
    float*       __restrict__ out)          // scratch sink (overwritten later)
{
    const int tid  = threadIdx.x;
    const int lane = tid & 63;
    const int wave = __builtin_amdgcn_readfirstlane(tid >> 6);
    const int b   = blockIdx.x & 7;
    const int bib = blockIdx.x >> 3;
    const unsigned short* fb = fbf16 + (size_t)b * ((size_t)PP * CIN);
    const int q     = lane & 15;
    const int permb = (lane & 48) << 2;
    const int kg = (bib * 8 + wave) * 16;
    const size_t rg = (size_t)b * KK + (size_t)kg;

    int   vld[4], idd[4];
    float rl0[4], rl1[4], rl2[4];
#pragma unroll
    for (int qd = 0; qd < 4; ++qd) {
        const size_t rq = rg + (size_t)(qd * 4);
        vld[qd] = neighbor_valid[rq * NN + lane];
        idd[qd] = n_idxs[rq * NN + lane];
        const float* relq = neighbor_rel + rq * (NN * REL);
        rl0[qd] = relq[3 * lane + 0];
        rl1[qd] = relq[3 * lane + 1];
        rl2[qd] = relq[3 * lane + 2];
    }

    float s0 = 0.f, s1 = 0.f, s2 = 0.f, s3 = 0.f, cnt = 0.f, mracc = 0.f;
    for (int qd = 0; qd < 4; ++qd) {
        const int   cmb = idd[qd] | (vld[qd] << 14);
        const float msf = (float)vld[qd];
        mracc += msf * (rl0[qd] + rl1[qd] + rl2[qd]);   // keep rel loads live

        int cm[NN];
#pragma unroll
        for (int n = 0; n < NN; ++n)
            cm[n] = __builtin_amdgcn_ds_bpermute(permb + 4 * n, cmb);

        u32x2 gv[NN];
#pragma unroll
        for (int n = 0; n < NN; ++n) {
            const int off = ((cm[n] & 0x3FFF) << 6) + 4 * q;
            gv[n] = *(const u32x2*)(fb + off);
        }
        __builtin_amdgcn_sched_barrier(0);

#pragma unroll
        for (int n = 0; n < NN; ++n) {
            const float m = (float)(cm[n] >> 14);
            cnt += m;
            const unsigned ux = gv[n].x, uy = gv[n].y;
            s0 = fmaf(m, __uint_as_float(ux << 16), s0);
            s1 = fmaf(m, __uint_as_float(ux & 0xFFFF0000u), s1);
            s2 = fmaf(m, __uint_as_float(uy << 16), s2);
            s3 = fmaf(m, __uint_as_float(uy & 0xFFFF0000u), s3);
        }
    }
    // one live store per thread keeps everything above un-DCE'd
    out[(size_t)blockIdx.x * 512 + tid] = s0 + s1 + s2 + s3 + cnt + mracc;
}

// ============== PROBE B: full kernel with gathers stubbed ==============
__global__ __launch_bounds__(512, 4)
void probe_nogather_kernel(
    const int*   __restrict__ n_idxs,
    const float* __restrict__ neighbor_rel,
    const int*   __restrict__ neighbor_valid,
    const float* __restrict__ Wm,
    const float* __restrict__ bvec,
    float*       __restrict__ out)          // garbage; overwritten later
{
    __shared__ __align__(16) unsigned short Wbf[OUTC * PITCH_US];
    __shared__ __align__(16) unsigned short Stile[8 * 16 * PITCH_US];

    const int tid = threadIdx.x;
    {
        unsigned int* w32 = (unsigned int*)Wbf;
        for (int j = tid; j < OUTC * (PITCH_US / 2); j += 512) {
            const int o = j / (PITCH_US / 2);
            const int d = j - o * (PITCH_US / 2);
            const int c0 = 2 * d, c1 = 2 * d + 1;
            const float w0 = (c0 < CC) ? Wm[o * CC + c0] : 0.0f;
            const float w1 = (c1 < CC) ? Wm[o * CC + c1] : 0.0f;
            w32[j] = (unsigned int)bf16_rne(w0) |
                     ((unsigned int)bf16_rne(w1) << 16);
        }
    }
    __syncthreads();

    const int lane = tid & 63;
    const int wave = __builtin_amdgcn_readfirstlane(tid >> 6);
    unsigned short* Sw = &Stile[wave * 16 * PITCH_US];
    {
        unsigned int* s32 = (unsigned int*)Sw;
        for (int j = lane; j < 16 * (PITCH_US / 2); j += 64) s32[j] = 0u;
    }

    const int b   = blockIdx.x & 7;
    const int bib = blockIdx.x >> 3;
    const int q     = lane & 15;
    const int permb = (lane & 48) << 2;
    const int kg = (bib * 8 + wave) * 16;
    const size_t rg = (size_t)b * KK + (size_t)kg;

    int   vld[4], idd[4];
    float rl0[4], rl1[4], rl2[4];
#pragma unroll
    for (int qd = 0; qd < 4; ++qd) {
        const size_t rq = rg + (size_t)(qd * 4);
        vld[qd] = neighbor_valid[rq * NN + lane];
        idd[qd] = n_idxs[rq * NN + lane];
        const float* relq = neighbor_rel + rq * (NN * REL);
        rl0[qd] = relq[3 * lane + 0];
        rl1[qd] = relq[3 * lane + 1];
        rl2[qd] = relq[3 * lane + 2];
    }

    for (int qd = 0; qd < 4; ++qd) {
        const int   cmb = idd[qd] | (vld[qd] << 14);
        const float msf = (float)vld[qd];
        float mr0 = msf * rl0[qd];
        float mr1 = msf * rl1[qd];
        float mr2 = msf * rl2[qd];
        float cnt = 0.f;

        int cm[NN];
#pragma unroll
        for (int n = 0; n < NN; ++n)
            cm[n] = __builtin_amdgcn_ds_bpermute(permb + 4 * n, cmb);

        // ---- gathers STUBBED: finite synthetic bf16 halves (2 VALU) ----
        u32x2 gv[NN];
#pragma unroll
        for (int n = 0; n < NN; ++n) {
            const unsigned h = 0x3C00u | (unsigned)(cm[n] & 0xFF);
            gv[n].x = h | (h << 16);
            gv[n].y = gv[n].x;
        }

        float s0 = 0.f, s1 = 0.f, s2 = 0.f, s3 = 0.f;
#pragma unroll
        for (int n = 0; n < NN; ++n) {
            const float m = (float)(cm[n] >> 14);
            cnt += m;
            const unsigned ux = gv[n].x, uy = gv[n].y;
            s0 = fmaf(m, __uint_as_float(ux << 16), s0);
            s1 = fmaf(m, __uint_as_float(ux & 0xFFFF0000u), s1);
            s2 = fmaf(m, __uint_as_float(uy << 16), s2);
            s3 = fmaf(m, __uint_as_float(uy & 0xFFFF0000u), s3);
        }

        mr0 = swz_add<0x041F>(mr0); mr1 = swz_add<0x041F>(mr1); mr2 = swz_add<0x041F>(mr2);
        mr0 = swz_add<0x081F>(mr0); mr1 = swz_add<0x081F>(mr1); mr2 = swz_add<0x081F>(mr2);
        mr0 = swz_add<0x101F>(mr0); mr1 = swz_add<0x101F>(mr1); mr2 = swz_add<0x101F>(mr2);
        mr0 = swz_add<0x201F>(mr0); mr1 = swz_add<0x201F>(mr1); mr2 = swz_add<0x201F>(mr2);

        const float inv = (cnt > 0.f) ? (1.0f / cnt) : 0.0f;
        const int rowl = qd * 4 + (lane >> 4);
        u32x2 pv;
        pv.x = (unsigned)bf16_rne(s0 * inv) |
               ((unsigned)bf16_rne(s1 * inv) << 16);
        pv.y = (unsigned)bf16_rne(s2 * inv) |
               ((unsigned)bf16_rne(s3 * inv) << 16);
        *(u32x2*)(&Sw[rowl * PITCH_US + 4 * q]) = pv;
        if (q == 0) {
            u32x2 ev;
            ev.x = (unsigned)bf16_rne(mr0 * inv) |
                   ((unsigned)bf16_rne(mr1 * inv) << 16);
            ev.y = (unsigned)bf16_rne(mr2 * inv);
            *(u32x2*)(&Sw[rowl * PITCH_US + 64]) = ev;
        }
    }

    f32x4 C0 = {0.f,0.f,0.f,0.f}, C1 = {0.f,0.f,0.f,0.f};
    f32x4 C2 = {0.f,0.f,0.f,0.f}, C3 = {0.f,0.f,0.f,0.f};
#pragma unroll
    for (int p = 0; p < 3; ++p) {
        const int ko = p * 32 + (lane >> 4) * 8;
        const s16x8 A  = *(const s16x8*)&Sw[(lane & 15) * PITCH_US + ko];
        const s16x8 B0 = *(const s16x8*)&Wbf[( 0 + (lane & 15)) * PITCH_US + ko];
        const s16x8 B1 = *(const s16x8*)&Wbf[(16 + (lane & 15)) * PITCH_US + ko];
        const s16x8 B2 = *(const s16x8*)&Wbf[(32 + (lane & 15)) * PITCH_US + ko];
        const s16x8 B3 = *(const s16x8*)&Wbf[(48 + (lane & 15)) * PITCH_US + ko];
        C0 = __builtin_amdgcn_mfma_f32_16x16x32_bf16(A, B0, C0, 0, 0, 0);
        C1 = __builtin_amdgcn_mfma_f32_16x16x32_bf16(A, B1, C1, 0, 0, 0);
        C2 = __builtin_amdgcn_mfma_f32_16x16x32_bf16(A, B2, C2, 0, 0, 0);
        C3 = __builtin_amdgcn_mfma_f32_16x16x32_bf16(A, B3, C3, 0, 0, 0);
    }

    const float bias0 = bvec[ 0 + (lane & 15)];
    const float bias1 = bvec[16 + (lane & 15)];
    const float bias2 = bvec[32 + (lane & 15)];
    const float bias3 = bvec[48 + (lane & 15)];
    const int m0 = (lane >> 4) * 4;
    const int oc = lane & 15;
#pragma unroll
    for (int r = 0; r < 4; ++r) {
        const size_t orow = ((size_t)b * KK + (size_t)(kg + m0 + r)) * OUTC;
        out[orow + 0  + oc] = fmaxf(C0[r] + bias0, 0.0f);
        out[orow + 16 + oc] = fmaxf(C1[r] + bias1, 0.0f);
        out[orow + 32 + oc] = fmaxf(C2[r] + bias2, 0.0f);
        out[orow + 48 + oc] = fmaxf(C3[r] + bias3, 0.0f);
    }
}

// ==================== REAL KERNEL (r13 body, 44us) ====================
__global__ __launch_bounds__(512, 4)
void graphconv_kernel(
    const unsigned short* __restrict__ fbf16,
    const int*   __restrict__ n_idxs,
    const float* __restrict__ neighbor_rel,
    const int*   __restrict__ neighbor_valid,
    const float* __restrict__ Wm,
    const float* __restrict__ bvec,
    float*       __restrict__ out)
{
    __shared__ __align__(16) unsigned short Wbf[OUTC * PITCH_US];
    __shared__ __align__(16) unsigned short Stile[8 * 16 * PITCH_US];

    const int tid = threadIdx.x;
    {
        unsigned int* w32 = (unsigned int*)Wbf;
        for (int j = tid; j < OUTC * (PITCH_US / 2); j += 512) {
            const int o = j / (PITCH_US / 2);
            const int d = j - o * (PITCH_US / 2);
            const int c0 = 2 * d, c1 = 2 * d + 1;
            const float w0 = (c0 < CC) ? Wm[o * CC + c0] : 0.0f;
            const float w1 = (c1 < CC) ? Wm[o * CC + c1] : 0.0f;
            w32[j] = (unsigned int)bf16_rne(w0) |
                     ((unsigned int)bf16_rne(w1) << 16);
        }
    }
    __syncthreads();

    const int lane = tid & 63;
    const int wave = __builtin_amdgcn_readfirstlane(tid >> 6);
    unsigned short* Sw = &Stile[wave * 16 * PITCH_US];
    {
        unsigned int* s32 = (unsigned int*)Sw;
        for (int j = lane; j < 16 * (PITCH_US / 2); j += 64) s32[j] = 0u;
    }

    const int b   = blockIdx.x & 7;
    const int bib = blockIdx.x >> 3;
    const unsigned short* fb = fbf16 + (size_t)b * ((size_t)PP * CIN);
    const int q     = lane & 15;
    const int permb = (lane & 48) << 2;
    const int kg = (bib * 8 + wave) * 16;
    const size_t rg = (size_t)b * KK + (size_t)kg;

    int   vld[4], idd[4];
    float rl0[4], rl1[4], rl2[4];
#pragma unroll
    for (int qd = 0; qd < 4; ++qd) {
        const size_t rq = rg + (size_t)(qd * 4);
        vld[qd] = neighbor_valid[rq * NN + lane];
        idd[qd] = n_idxs[rq * NN + lane];
        const float* relq = neighbor_rel + rq * (NN * REL);
        rl0[qd] = relq[3 * lane + 0];
        rl1[qd] = relq[3 * lane + 1];
        rl2[qd] = relq[3 * lane + 2];
    }

    for (int qd = 0; qd < 4; ++qd) {
        const int   cmb = idd[qd] | (vld[qd] << 14);
        const float msf = (float)vld[qd];
        float mr0 = msf * rl0[qd];
        float mr1 = msf * rl1[qd];
        float mr2 = msf * rl2[qd];
        float cnt = msf;

        int cm[NN];
#pragma unroll
        for (int n = 0; n < NN; ++n)
            cm[n] = __builtin_amdgcn_ds_bpermute(permb + 4 * n, cmb);

        u32x2 gv[NN];
#pragma unroll
        for (int n = 0; n < NN; ++n) {
            const int off = ((cm[n] & 0x3FFF) << 6) + 4 * q;
            gv[n] = *(const u32x2*)(fb + off);
        }
        __builtin_amdgcn_sched_barrier(0);

        float s0 = 0.f, s1 = 0.f, s2 = 0.f, s3 = 0.f;
#pragma unroll
        for (int n = 0; n < NN; ++n) {
            const float m = (float)(cm[n] >> 14);
            const unsigned ux = gv[n].x, uy = gv[n].y;
            s0 = fmaf(m, __uint_as_float(ux << 16), s0);
            s1 = fmaf(m, __uint_as_float(ux & 0xFFFF0000u), s1);
            s2 = fmaf(m, __uint_as_float(uy << 16), s2);
            s3 = fmaf(m, __uint_as_float(uy & 0xFFFF0000u), s3);
        }

        cnt = swz_add<0x041F>(cnt); mr0 = swz_add<0x041F>(mr0);
        mr1 = swz_add<0x041F>(mr1); mr2 = swz_add<0x041F>(mr2);
        cnt = swz_add<0x081F>(cnt); mr0 = swz_add<0x081F>(mr0);
        mr1 = swz_add<0x081F>(mr1); mr2 = swz_add<0x081F>(mr2);
        cnt = swz_add<0x101F>(cnt); mr0 = swz_add<0x101F>(mr0);
        mr1 = swz_add<0x101F>(mr1); mr2 = swz_add<0x101F>(mr2);
        cnt = swz_add<0x201F>(cnt); mr0 = swz_add<0x201F>(mr0);
        mr1 = swz_add<0x201F>(mr1); mr2 = swz_add<0x201F>(mr2);

        const float inv = (cnt > 0.f) ? (1.0f / cnt) : 0.0f;
        const int rowl = qd * 4 + (lane >> 4);
        u32x2 pv;
        pv.x = (unsigned)bf16_rne(s0 * inv) |
               ((unsigned)bf16_rne(s1 * inv) << 16);
        pv.y = (unsigned)bf16_rne(s2 * inv) |
               ((unsigned)bf16_rne(s3 * inv) << 16);
        *(u32x2*)(&Sw[rowl * PITCH_US + 4 * q]) = pv;
        if (q == 0) {
            u32x2 ev;
            ev.x = (unsigned)bf16_rne(mr0 * inv) |
                   ((unsigned)bf16_rne(mr1 * inv) << 16);
            ev.y = (unsigned)bf16_rne(mr2 * inv);
            *(u32x2*)(&Sw[rowl * PITCH_US + 64]) = ev;
        }
    }

    f32x4 C0 = {0.f,0.f,0.f,0.f}, C1 = {0.f,0.f,0.f,0.f};
    f32x4 C2 = {0.f,0.f,0.f,0.f}, C3 = {0.f,0.f,0.f,0.f};
#pragma unroll
    for (int p = 0; p < 3; ++p) {
        const int ko = p * 32 + (lane >> 4) * 8;
        const s16x8 A  = *(const s16x8*)&Sw[(lane & 15) * PITCH_US + ko];
        const s16x8 B0 = *(const s16x8*)&Wbf[( 0 + (lane & 15)) * PITCH_US + ko];
        const s16x8 B1 = *(const s16x8*)&Wbf[(16 + (lane & 15)) * PITCH_US + ko];
        const s16x8 B2 = *(const s16x8*)&Wbf[(32 + (lane & 15)) * PITCH_US + ko];
        const s16x8 B3 = *(const s16x8*)&Wbf[(48 + (lane & 15)) * PITCH_US + ko];
        C0 = __builtin_amdgcn_mfma_f32_16x16x32_bf16(A, B0, C0, 0, 0, 0);
        C1 = __builtin_amdgcn_mfma_f32_16x16x32_bf16(A, B1, C1, 0, 0, 0);
        C2 = __builtin_amdgcn_mfma_f32_16x16x32_bf16(A, B2, C2, 0, 0, 0);
        C3 = __builtin_amdgcn_mfma_f32_16x16x32_bf16(A, B3, C3, 0, 0, 0);
    }

    const float bias0 = bvec[ 0 + (lane & 15)];
    const float bias1 = bvec[16 + (lane & 15)];
    const float bias2 = bvec[32 + (lane & 15)];
    const float bias3 = bvec[48 + (lane & 15)];
    const int m0 = (lane >> 4) * 4;
    const int oc = lane & 15;
#pragma unroll
    for (int r = 0; r < 4; ++r) {
        const size_t orow = ((size_t)b * KK + (size_t)(kg + m0 + r)) * OUTC;
        out[orow + 0  + oc] = fmaxf(C0[r] + bias0, 0.0f);
        out[orow + 16 + oc] = fmaxf(C1[r] + bias1, 0.0f);
        out[orow + 32 + oc] = fmaxf(C2[r] + bias2, 0.0f);
        out[orow + 48 + oc] = fmaxf(C3[r] + bias3, 0.0f);
    }
}

extern "C" void kernel_launch(void* const* d_in, const int* in_sizes, int n_in,
                              void* d_out, int out_size, void* d_ws, size_t ws_size,
                              hipStream_t stream) {
    const float* feats = (const float*)d_in[2];
    const int*   nidx  = (const int*)  d_in[3];
    const float* nrel  = (const float*)d_in[4];
    const int*   nval  = (const int*)  d_in[5];
    const float* Wm    = (const float*)d_in[6];
    const float* bv    = (const float*)d_in[7];
    float* out = (float*)d_out;

    unsigned short* fbf16 = (unsigned short*)d_ws;

    // pre-pass (unchanged)
    feats_to_bf16_kernel<<<dim3(8192), dim3(256), 0, stream>>>(feats, fbf16);

    // --- probes (diagnostic; both write to out, overwritten below) ---
    probe_gather_kernel<<<dim3(1024), dim3(512), 0, stream>>>(
        fbf16, nidx, nrel, nval, out);
    probe_nogather_kernel<<<dim3(1024), dim3(512), 0, stream>>>(
        nidx, nrel, nval, Wm, bv, out);

    // --- real kernel LAST: fully overwrites out ---
    graphconv_kernel<<<dim3(1024), dim3(512), 0, stream>>>(
        fbf16, nidx, nrel, nval, Wm, bv, out);
}